// Round 10
// baseline (346.353 us; speedup 1.0000x reference)
//
#include <hip/hip_runtime.h>
#include <hip/hip_bf16.h>
#include <stdint.h>

// Problem constants
constexpr int IN_F  = 4096;
constexpr int OUT_F = 4096;
constexpr int M_ROWS = 4 * 2048;   // 8192
constexpr int RANK = 16;

typedef short short8 __attribute__((ext_vector_type(8)));
typedef float f32x4 __attribute__((ext_vector_type(4)));

__device__ __forceinline__ short f2bf(float f) {
  return __builtin_bit_cast(short, __float2bfloat16(f));
}

__device__ __forceinline__ void gload16(const void* g, void* l) {
  __builtin_amdgcn_global_load_lds(
      (const __attribute__((address_space(1))) void*)g,
      (__attribute__((address_space(3))) void*)l, 16, 0, 0);
}

// ---------------------------------------------------------------------------
// Kernel 1 (fused): blocks 0..511 dequantize+LoRA-fold W_eff; blocks 512..2559
// convert x fp32->bf16.
// ---------------------------------------------------------------------------
__global__ __launch_bounds__(256) void prep_kernel(
    const int* __restrict__ q,        // packed bytes, one byte per int32
    const float* __restrict__ wmax,
    const float* __restrict__ lut,
    const float* __restrict__ lA,     // [RANK][IN_F]
    const float* __restrict__ lB,     // [OUT_F][RANK]
    const float* __restrict__ x,
    __hip_bfloat16* __restrict__ W,   // [OUT_F][IN_F]
    __hip_bfloat16* __restrict__ xb) {
  if (blockIdx.x < 512) {
    __shared__ float slut[16];
    if (threadIdx.x < 16) slut[threadIdx.x] = lut[threadIdx.x];
    __syncthreads();

    const int bx = blockIdx.x & 7, by = blockIdx.x >> 3;
    const int o0  = by * 64 + (threadIdx.x >> 5) * 8;
    const int ib0 = bx * 512 + (threadIdx.x & 31) * 16;

    #pragma unroll
    for (int h = 0; h < 2; ++h) {
      const int ib = ib0 + h * 8;
      float w[8][8];
      #pragma unroll
      for (int p = 0; p < 8; ++p) {
        const size_t l = (size_t)(o0 + p) * IN_F + ib;
        const int4 u = *(const int4*)(q + (l >> 1));
        const float sc = wmax[l >> 6];
        w[p][0] = slut[u.x & 15] * sc;
        w[p][1] = slut[(u.x >> 4) & 15] * sc;
        w[p][2] = slut[u.y & 15] * sc;
        w[p][3] = slut[(u.y >> 4) & 15] * sc;
        w[p][4] = slut[u.z & 15] * sc;
        w[p][5] = slut[(u.z >> 4) & 15] * sc;
        w[p][6] = slut[u.w & 15] * sc;
        w[p][7] = slut[(u.w >> 4) & 15] * sc;
      }
      #pragma unroll 2
      for (int r = 0; r < 16; ++r) {
        const float* ar = lA + (size_t)r * IN_F + ib;
        const float4 a0 = *(const float4*)(ar);
        const float4 a1 = *(const float4*)(ar + 4);
        float b[8];
        #pragma unroll
        for (int p = 0; p < 8; ++p) b[p] = lB[(size_t)(o0 + p) * RANK + r];
        #pragma unroll
        for (int p = 0; p < 8; ++p) {
          w[p][0] += b[p] * a0.x; w[p][1] += b[p] * a0.y;
          w[p][2] += b[p] * a0.z; w[p][3] += b[p] * a0.w;
          w[p][4] += b[p] * a1.x; w[p][5] += b[p] * a1.y;
          w[p][6] += b[p] * a1.z; w[p][7] += b[p] * a1.w;
        }
      }
      #pragma unroll
      for (int p = 0; p < 8; ++p) {
        short8 s;
        #pragma unroll
        for (int qq = 0; qq < 8; ++qq) s[qq] = f2bf(w[p][qq]);
        *(short8*)&W[(size_t)(o0 + p) * IN_F + ib] = s;
      }
    }
  } else {
    constexpr int NG = (M_ROWS * IN_F) / 8;
    const int stride = 2048 * 256;
    for (int i = (blockIdx.x - 512) * 256 + threadIdx.x; i < NG; i += stride) {
      const float4 a = ((const float4*)x)[2 * i];
      const float4 b = ((const float4*)x)[2 * i + 1];
      short8 s;
      s[0] = f2bf(a.x); s[1] = f2bf(a.y); s[2] = f2bf(a.z); s[3] = f2bf(a.w);
      s[4] = f2bf(b.x); s[5] = f2bf(b.y); s[6] = f2bf(b.z); s[7] = f2bf(b.w);
      ((short8*)xb)[i] = s;
    }
  }
}

// ---------------------------------------------------------------------------
// Kernel 2: 256x128-tile bf16 MFMA GEMM — 2 blocks/CU occupancy, VGPR-safe.
// 4 waves (2Mx2N), per-wave 128x64 output (acc[8][4] = 128 regs; 2 waves/SIMD
// budget 256 -> no spill, unlike R7; tile big enough to avoid R8's fetch
// explosion: staging 96 B/output vs R3's 64, vs R8's 160).
// LDS 48 KiB: sA[2][256][32] + sB[2][128][32] -> 2 blocks/CU co-resident;
// cross-block overlap (m114) fills each block's LDS/barrier serial time —
// the per-block K-loop is ~85% non-MFMA and 7 schedule variants at
// 1 block/CU all pinned at 283-304 us.
// Per K-tile (BK=32): [stage(t+1): 6 gload_lds; vmcnt(6) counted (drains
// exactly tile t's 6, never 0); barrier; 12 ds_read_b128; setprio(1);
// 32 MFMA; setprio(0); barrier].
// Slot-XOR swizzle identical to R3 (regions [.][32], 64B rows): physical
// granule (row,sp) holds global slot sp^((row>>1)&3); linear gload dest +
// pre-swizzled source + same XOR on read => 0 bank conflicts (R3-measured).
// ---------------------------------------------------------------------------
constexpr int BM = 256, BN = 128, BK = 32;
constexpr int GM = M_ROWS, GN = OUT_F, GK = IN_F;
constexpr int NKT = GK / BK;  // 128

__global__ __launch_bounds__(256, 2) void gemm_bt_2blk(
    const __hip_bfloat16* __restrict__ A,  // [M][K] bf16
    const __hip_bfloat16* __restrict__ B,  // [N][K] bf16
    const float* __restrict__ bias,        // [N]
    float* __restrict__ C) {               // [M][N] fp32
  __shared__ __hip_bfloat16 sA[2][256][32];  // 32 KiB
  __shared__ __hip_bfloat16 sB[2][128][32];  // 16 KiB

  const int tid  = threadIdx.x;
  const int lane = tid & 63;
  const int wave = tid >> 6;    // 0..3
  const int lr = lane & 15;
  const int lk = lane >> 4;
  const int wm = wave >> 1;     // 0..1 (M half)
  const int wn = wave & 1;      // 0..1 (N half)
  // fragment rows differ from lr by multiples of 16 -> per-lane constant
  const int swr = lk ^ ((lr >> 1) & 3);

  // T1: XCD-aware swizzle (nwg=1024, %8==0 -> bijective)
  const int bid = blockIdx.x;
  const int cpx = gridDim.x >> 3;
  const int wg  = (bid & 7) * cpx + (bid >> 3);
  const int nbn = GN / BN;      // 32
  const int m0 = (wg / nbn) * BM;
  const int n0 = (wg % nbn) * BN;

  const __hip_bfloat16* Abase = A + (size_t)m0 * GK;
  const __hip_bfloat16* Bbase = B + (size_t)n0 * GK;

  // Staging: A-region 256x32 (1024 granules, 4 instr/thread), B-region
  // 128x32 (512 granules, 2 instr/thread).  Granule c: row=c>>2, slot=c&3;
  // physical slot receives global slot^swst, swst=(row>>1)&3=(tid>>3)&3
  // (row parity identical for all of one thread's granules: c steps by 256).
  const int swst = (tid >> 3) & 3;
  auto stageA = [&](const __hip_bfloat16* gb, __hip_bfloat16* lb) {
    #pragma unroll
    for (int k = 0; k < 4; ++k) {
      const int c = k * 256 + tid;
      const int row = c >> 2, slot = c & 3;
      gload16(gb + (size_t)row * GK + (size_t)((slot ^ swst) * 8),
              (void*)((char*)lb + (k * 256 + wave * 64) * 16));
    }
  };
  auto stageB = [&](const __hip_bfloat16* gb, __hip_bfloat16* lb) {
    #pragma unroll
    for (int k = 0; k < 2; ++k) {
      const int c = k * 256 + tid;
      const int row = c >> 2, slot = c & 3;
      gload16(gb + (size_t)row * GK + (size_t)((slot ^ swst) * 8),
              (void*)((char*)lb + (k * 256 + wave * 64) * 16));
    }
  };

  f32x4 acc[8][4];
  #pragma unroll
  for (int m = 0; m < 8; ++m)
    #pragma unroll
    for (int n = 0; n < 4; ++n) acc[m][n] = (f32x4)0.0f;

  // Prologue: stage tile 0 (6 VMEM instr outstanding).
  stageA(Abase, &sA[0][0][0]);
  stageB(Bbase, &sB[0][0][0]);

  for (int t = 0; t < NKT; ++t) {
    const int buf = t & 1;
    const int tn = (t + 1 < NKT) ? t + 1 : t;  // tail restage -> unread buffer
    stageA(Abase + (size_t)tn * BK, &sA[buf ^ 1][0][0]);
    stageB(Bbase + (size_t)tn * BK, &sB[buf ^ 1][0][0]);
    // 12 outstanding; wait to 6 -> tile t's 6 complete (oldest drain, m135)
    asm volatile("s_waitcnt vmcnt(6)" ::: "memory");
    __builtin_amdgcn_s_barrier();

    short8 af[8], bf[4];
    #pragma unroll
    for (int n = 0; n < 4; ++n)
      bf[n] = *(const short8*)&sB[buf][wn * 64 + n * 16 + lr][swr * 8];
    #pragma unroll
    for (int m = 0; m < 8; ++m)
      af[m] = *(const short8*)&sA[buf][wm * 128 + m * 16 + lr][swr * 8];

    __builtin_amdgcn_s_setprio(1);
    #pragma unroll
    for (int m = 0; m < 8; ++m)
      #pragma unroll
      for (int n = 0; n < 4; ++n)
        acc[m][n] = __builtin_amdgcn_mfma_f32_16x16x32_bf16(
            af[m], bf[n], acc[m][n], 0, 0, 0);
    __builtin_amdgcn_s_setprio(0);
    __builtin_amdgcn_sched_barrier(0);
    __builtin_amdgcn_s_barrier();
  }

  // epilogue: C = acc + bias
  #pragma unroll
  for (int n = 0; n < 4; ++n) {
    const int col = n0 + wn * 64 + n * 16 + lr;
    const float bv = bias[col];
    #pragma unroll
    for (int m = 0; m < 8; ++m) {
      const int row = m0 + wm * 128 + m * 16 + lk * 4;
      #pragma unroll
      for (int j = 0; j < 4; ++j)
        C[(size_t)(row + j) * GN + col] = acc[m][n][j] + bv;
    }
  }
}

// ---------------------------------------------------------------------------
extern "C" void kernel_launch(void* const* d_in, const int* in_sizes, int n_in,
                              void* d_out, int out_size, void* d_ws, size_t ws_size,
                              hipStream_t stream) {
  const float* x    = (const float*)d_in[0];
  const int*   qw   = (const int*)d_in[1];
  const float* wmax = (const float*)d_in[2];
  const float* lut  = (const float*)d_in[3];
  const float* lA   = (const float*)d_in[4];
  const float* lB   = (const float*)d_in[5];
  const float* bias = (const float*)d_in[6];
  float* out = (float*)d_out;

  __hip_bfloat16* Weff = (__hip_bfloat16*)d_ws;                       // 33.5 MB
  __hip_bfloat16* xb   = (__hip_bfloat16*)((char*)d_ws + (size_t)OUT_F * IN_F * 2); // 67 MB

  prep_kernel<<<2560, 256, 0, stream>>>(qw, wmax, lut, lA, lB, x, Weff, xb);
  gemm_bt_2blk<<<(GM / BM) * (GN / BN), 256, 0, stream>>>(xb, Weff, bias, out);
}

// Round 11
// 341.072 us; speedup vs baseline: 1.0155x; 1.0155x over previous
//
#include <hip/hip_runtime.h>
#include <hip/hip_bf16.h>
#include <stdint.h>

// Problem constants
constexpr int IN_F  = 4096;
constexpr int OUT_F = 4096;
constexpr int M_ROWS = 4 * 2048;   // 8192
constexpr int RANK = 16;

typedef short short8 __attribute__((ext_vector_type(8)));
typedef float f32x16 __attribute__((ext_vector_type(16)));

__device__ __forceinline__ short f2bf(float f) {
  return __builtin_bit_cast(short, __float2bfloat16(f));
}

__device__ __forceinline__ void gload16(const void* g, void* l) {
  __builtin_amdgcn_global_load_lds(
      (const __attribute__((address_space(1))) void*)g,
      (__attribute__((address_space(3))) void*)l, 16, 0, 0);
}

// ---------------------------------------------------------------------------
// Kernel 1 (fused): blocks 0..511 dequantize+LoRA-fold W_eff; blocks 512..2559
// convert x fp32->bf16.
// ---------------------------------------------------------------------------
__global__ __launch_bounds__(256) void prep_kernel(
    const int* __restrict__ q,        // packed bytes, one byte per int32
    const float* __restrict__ wmax,
    const float* __restrict__ lut,
    const float* __restrict__ lA,     // [RANK][IN_F]
    const float* __restrict__ lB,     // [OUT_F][RANK]
    const float* __restrict__ x,
    __hip_bfloat16* __restrict__ W,   // [OUT_F][IN_F]
    __hip_bfloat16* __restrict__ xb) {
  if (blockIdx.x < 512) {
    __shared__ float slut[16];
    if (threadIdx.x < 16) slut[threadIdx.x] = lut[threadIdx.x];
    __syncthreads();

    const int bx = blockIdx.x & 7, by = blockIdx.x >> 3;
    const int o0  = by * 64 + (threadIdx.x >> 5) * 8;
    const int ib0 = bx * 512 + (threadIdx.x & 31) * 16;

    #pragma unroll
    for (int h = 0; h < 2; ++h) {
      const int ib = ib0 + h * 8;
      float w[8][8];
      #pragma unroll
      for (int p = 0; p < 8; ++p) {
        const size_t l = (size_t)(o0 + p) * IN_F + ib;
        const int4 u = *(const int4*)(q + (l >> 1));
        const float sc = wmax[l >> 6];
        w[p][0] = slut[u.x & 15] * sc;
        w[p][1] = slut[(u.x >> 4) & 15] * sc;
        w[p][2] = slut[u.y & 15] * sc;
        w[p][3] = slut[(u.y >> 4) & 15] * sc;
        w[p][4] = slut[u.z & 15] * sc;
        w[p][5] = slut[(u.z >> 4) & 15] * sc;
        w[p][6] = slut[u.w & 15] * sc;
        w[p][7] = slut[(u.w >> 4) & 15] * sc;
      }
      #pragma unroll 2
      for (int r = 0; r < 16; ++r) {
        const float* ar = lA + (size_t)r * IN_F + ib;
        const float4 a0 = *(const float4*)(ar);
        const float4 a1 = *(const float4*)(ar + 4);
        float b[8];
        #pragma unroll
        for (int p = 0; p < 8; ++p) b[p] = lB[(size_t)(o0 + p) * RANK + r];
        #pragma unroll
        for (int p = 0; p < 8; ++p) {
          w[p][0] += b[p] * a0.x; w[p][1] += b[p] * a0.y;
          w[p][2] += b[p] * a0.z; w[p][3] += b[p] * a0.w;
          w[p][4] += b[p] * a1.x; w[p][5] += b[p] * a1.y;
          w[p][6] += b[p] * a1.z; w[p][7] += b[p] * a1.w;
        }
      }
      #pragma unroll
      for (int p = 0; p < 8; ++p) {
        short8 s;
        #pragma unroll
        for (int qq = 0; qq < 8; ++qq) s[qq] = f2bf(w[p][qq]);
        *(short8*)&W[(size_t)(o0 + p) * IN_F + ib] = s;
      }
    }
  } else {
    constexpr int NG = (M_ROWS * IN_F) / 8;
    const int stride = 2048 * 256;
    for (int i = (blockIdx.x - 512) * 256 + threadIdx.x; i < NG; i += stride) {
      const float4 a = ((const float4*)x)[2 * i];
      const float4 b = ((const float4*)x)[2 * i + 1];
      short8 s;
      s[0] = f2bf(a.x); s[1] = f2bf(a.y); s[2] = f2bf(a.z); s[3] = f2bf(a.w);
      s[4] = f2bf(b.x); s[5] = f2bf(b.y); s[6] = f2bf(b.z); s[7] = f2bf(b.w);
      ((short8*)xb)[i] = s;
    }
  }
}

// ---------------------------------------------------------------------------
// Kernel 2: 256x256-tile 8-phase GEMM, R5 schedule, MFMA shape switched to
// v_mfma_f32_32x32x16_bf16 (m119: 2495 TF vs 2176 for 16x16x32 -> ~17% fewer
// MFMA cycles; halves MFMA instruction count).  Per phase: 4 A-frag + 4
// B-frag ds_read_b128 (same as before) + 8 MFMA of 32x32x16.
// Frag layout (32x32x16): lane&31 = row, lane>>5 = k-group of 8; read slot =
// (kst*2 + (lane>>5)) ^ swz, swz = ((lane&31)>>1)&3 — bank-checked: each
// consecutive-8-lane group covers all 8 granule positions (conflict-free).
// C/D: col = lane&31, row = (reg&3) + 8*(reg>>2) + 4*(lane>>5)  [m74/m101].
// Everything else identical to R5 (283us): [256][32] K-half regions, slot-XOR
// swizzle (0 conflicts), gload_lds w16, XCD swizzle, vmcnt(6)@p4/p8 never 0.
// ---------------------------------------------------------------------------
constexpr int BM = 256, BN = 256, BK = 64;
constexpr int GM = M_ROWS, GN = OUT_F, GK = IN_F;
constexpr int NKT = GK / BK;  // 64

#define LOAD_B32(BUF, KH)                                                 \
  _Pragma("unroll")                                                       \
  for (int nt_ = 0; nt_ < 2; ++nt_)                                       \
    _Pragma("unroll")                                                     \
    for (int ks_ = 0; ks_ < 2; ++ks_)                                     \
      bf[nt_][ks_] = *(const short8*)&sB[BUF][KH][wn * 64 + nt_ * 32 + l31][(((ks_ * 2 + lhi) ^ swz) * 8)];

#define LOAD_A32(BUF, KH, MH)                                             \
  _Pragma("unroll")                                                       \
  for (int mt_ = 0; mt_ < 2; ++mt_)                                       \
    _Pragma("unroll")                                                     \
    for (int ks_ = 0; ks_ < 2; ++ks_)                                     \
      af[mt_][ks_] = *(const short8*)&sA[BUF][KH][wm * 128 + (MH) * 64 + mt_ * 32 + l31][(((ks_ * 2 + lhi) ^ swz) * 8)];

#define MFMA_Q32(MH)                                                      \
  __builtin_amdgcn_s_setprio(1);                                          \
  _Pragma("unroll")                                                       \
  for (int mt_ = 0; mt_ < 2; ++mt_)                                       \
    _Pragma("unroll")                                                     \
    for (int nt_ = 0; nt_ < 2; ++nt_)                                     \
      _Pragma("unroll")                                                   \
      for (int ks_ = 0; ks_ < 2; ++ks_)                                   \
        acc[(MH) * 2 + mt_][nt_] = __builtin_amdgcn_mfma_f32_32x32x16_bf16( \
            af[mt_][ks_], bf[nt_][ks_], acc[(MH) * 2 + mt_][nt_], 0, 0, 0); \
  __builtin_amdgcn_s_setprio(0);

#define PHASE(BUF, KH, MH, DOB, GB, LB, VM)                               \
  do {                                                                    \
    if (DOB) { LOAD_B32(BUF, KH) }                                        \
    LOAD_A32(BUF, KH, MH)                                                 \
    stage(GB, LB);                                                        \
    if (VM) asm volatile("s_waitcnt vmcnt(6)" ::: "memory");              \
    __builtin_amdgcn_s_barrier();                                         \
    MFMA_Q32(MH)                                                          \
    __builtin_amdgcn_sched_barrier(0);                                    \
    __builtin_amdgcn_s_barrier();                                         \
  } while (0)

__global__ __launch_bounds__(512, 2) void gemm_bt_32x32(
    const __hip_bfloat16* __restrict__ A,  // [M][K] bf16
    const __hip_bfloat16* __restrict__ B,  // [N][K] bf16
    const float* __restrict__ bias,        // [N]
    float* __restrict__ C) {               // [M][N] fp32
  __shared__ __hip_bfloat16 sA[2][2][256][32];  // 64 KiB
  __shared__ __hip_bfloat16 sB[2][2][256][32];  // 64 KiB

  const int tid  = threadIdx.x;
  const int lane = tid & 63;
  const int wave = tid >> 6;
  const int l31 = lane & 31;
  const int lhi = lane >> 5;
  const int wm = wave >> 2;   // 0..1
  const int wn = wave & 3;    // 0..3
  // fragment rows differ from l31 by multiples of 32 -> per-lane constant
  const int swz = (l31 >> 1) & 3;

  // T1: XCD-aware swizzle (nwg=512, %8==0 -> bijective)
  const int bid = blockIdx.x;
  const int cpx = gridDim.x >> 3;
  const int wg  = (bid & 7) * cpx + (bid >> 3);
  const int nbn = GN / BN;    // 16
  const int m0 = (wg / nbn) * BM;
  const int n0 = (wg % nbn) * BN;

  const __hip_bfloat16* Abase = A + (size_t)m0 * GK;
  const __hip_bfloat16* Bbase = B + (size_t)n0 * GK;

  // stage one 256x32 K-half region (16 KiB): 1024 granules, 2 gload16/thread.
  // Physical granule (row=c>>2, sp=c&3) receives global slot sp ^ ((row>>1)&3).
  const int swst = (tid >> 3) & 3;
  auto stage = [&](const __hip_bfloat16* gb, __hip_bfloat16* lb) {
    #pragma unroll
    for (int j = 0; j < 2; ++j) {
      const int c = j * 512 + tid;
      const int row = c >> 2, slot = c & 3;
      const int sg = slot ^ swst;
      gload16(gb + (size_t)row * GK + sg * 8,
              (void*)((char*)lb + (j * 512 + wave * 64) * 16));
    }
  };

  f32x16 acc[4][2];
  #pragma unroll
  for (int m = 0; m < 4; ++m)
    #pragma unroll
    for (int n = 0; n < 2; ++n) acc[m][n] = (f32x16)0.0f;

  // Prologue: tile0 fully + tile1 {Bk0, Ak0, Bk1} = 14 VMEM instr;
  // vmcnt(6) -> stages 1-4 (sA00,sB00,sA01,sB01) complete.
  stage(Abase +  0, &sA[0][0][0][0]);
  stage(Bbase +  0, &sB[0][0][0][0]);
  stage(Abase + 32, &sA[0][1][0][0]);
  stage(Bbase + 32, &sB[0][1][0][0]);
  stage(Bbase + 64, &sB[1][0][0][0]);
  stage(Abase + 64, &sA[1][0][0][0]);
  stage(Bbase + 96, &sB[1][1][0][0]);
  asm volatile("s_waitcnt vmcnt(6)" ::: "memory");
  __builtin_amdgcn_s_barrier();

  short8 af[2][2], bf[2][2];

  for (int t = 0; t < NKT; t += 2) {
    // clamp keeps vmcnt counting exact on the last iterations; clamped
    // stages land only in regions that are never read again.
    const int t2 = (t + 2 < NKT) ? t + 2 : NKT - 1;
    const int t3 = (t + 3 < NKT) ? t + 3 : NKT - 1;

    PHASE(0, 0, 0, true,  Abase + (size_t)(t + 1) * 64 + 32, &sA[1][1][0][0], false);
    PHASE(0, 0, 1, false, Bbase + (size_t)t2 * 64,           &sB[0][0][0][0], false);
    PHASE(0, 1, 0, true,  Abase + (size_t)t2 * 64,           &sA[0][0][0][0], false);
    PHASE(0, 1, 1, false, Bbase + (size_t)t2 * 64 + 32,      &sB[0][1][0][0], true);
    PHASE(1, 0, 0, true,  Abase + (size_t)t2 * 64 + 32,      &sA[0][1][0][0], false);
    PHASE(1, 0, 1, false, Bbase + (size_t)t3 * 64,           &sB[1][0][0][0], false);
    PHASE(1, 1, 0, true,  Abase + (size_t)t3 * 64,           &sA[1][0][0][0], false);
    PHASE(1, 1, 1, false, Bbase + (size_t)t3 * 64 + 32,      &sB[1][1][0][0], true);
  }

  // epilogue: C = acc + bias.  32x32 C/D: col=lane&31,
  // row = (reg&3) + 8*(reg>>2) + 4*(lane>>5).
  #pragma unroll
  for (int nt = 0; nt < 2; ++nt) {
    const int col = n0 + wn * 64 + nt * 32 + l31;
    const float bv = bias[col];
    #pragma unroll
    for (int amt = 0; amt < 4; ++amt) {
      const int rb = m0 + wm * 128 + amt * 32 + 4 * lhi;
      #pragma unroll
      for (int reg = 0; reg < 16; ++reg) {
        const int row = rb + (reg & 3) + 8 * (reg >> 2);
        C[(size_t)row * GN + col] = acc[amt][nt][reg] + bv;
      }
    }
  }
}

// ---------------------------------------------------------------------------
extern "C" void kernel_launch(void* const* d_in, const int* in_sizes, int n_in,
                              void* d_out, int out_size, void* d_ws, size_t ws_size,
                              hipStream_t stream) {
  const float* x    = (const float*)d_in[0];
  const int*   qw   = (const int*)d_in[1];
  const float* wmax = (const float*)d_in[2];
  const float* lut  = (const float*)d_in[3];
  const float* lA   = (const float*)d_in[4];
  const float* lB   = (const float*)d_in[5];
  const float* bias = (const float*)d_in[6];
  float* out = (float*)d_out;

  __hip_bfloat16* Weff = (__hip_bfloat16*)d_ws;                       // 33.5 MB
  __hip_bfloat16* xb   = (__hip_bfloat16*)((char*)d_ws + (size_t)OUT_F * IN_F * 2); // 67 MB

  prep_kernel<<<2560, 256, 0, stream>>>(qw, wmax, lut, lA, lB, x, Weff, xb);
  gemm_bt_32x32<<<(GM / BM) * (GN / BN), 512, 0, stream>>>(xb, Weff, bias, out);
}